// Round 2
// 197.584 us; speedup vs baseline: 1.0176x; 1.0176x over previous
//
#include <hip/hip_runtime.h>
#include <cstdint>
#include <cstddef>

// Problem dims (fixed by the reference setup_inputs):
#define B_DIM   8192
#define IN_DIM  1024
#define OUT_DIM 4096
#define KT2     (IN_DIM / 64)    // 16 panels (of K=64) per 32-row tile

typedef __attribute__((ext_vector_type(8)))  int   i32x8;   // fp8 MFMA A/B frag (32 B)
typedef __attribute__((ext_vector_type(4)))  int   i32x4;
typedef __attribute__((ext_vector_type(16))) float f32x16;  // 32x32 MFMA accumulator

// async global->LDS DMA, 16B per lane. LDS dest is wave-uniform base + lane*16.
__device__ __forceinline__ void async_copy16(const void* gptr, void* ldsptr) {
    __builtin_amdgcn_global_load_lds(
        (__attribute__((address_space(1))) void*)gptr,
        (__attribute__((address_space(3))) void*)ldsptr,
        16, 0, 0);
}

// pack 4 fp32 -> 4 OCP e4m3 bytes (little-endian k order)
__device__ __forceinline__ int pack4_fp8(float a, float b, float c, float d) {
    int pk = __builtin_amdgcn_cvt_pk_fp8_f32(a, b, 0, false);   // bytes 0-1
    pk = __builtin_amdgcn_cvt_pk_fp8_f32(c, d, pk, true);       // bytes 2-3
    return pk;
}

// fp8 panel: 32 rows x 64 k = 2048 B. Lane l owns row m=l&31, k=(l>>5)*32+[0,32).
// Stored pre-split into the two 1KB DMA halves: half h lives at panel + h*1024 + l*16.
// Staging is fully-linear global_load_lds; frag reads are two ds_read_b128 at
// base + lane*16 (conflict-free m97/m134 pattern — no swizzle needed).

// ---------------------------------------------------------------------------
// Kernel 1: x (fp32, B x IN row-major) -> fp8 A panels + xsq (exact fp32).
// 512 threads (8 waves -> 2 waves/SIMD for load MLP). Block = one mt (32 rows);
// wave w emits panels kt2 = c*8+w, c=0..1. Blocks 0..7 also zero wsq.
// ---------------------------------------------------------------------------
__global__ __launch_bounds__(512) void tile_x_kernel(
    const float* __restrict__ x, unsigned char* __restrict__ At,
    float* __restrict__ xsq, float* __restrict__ wsq)
{
    const int t = threadIdx.x;
    const int w = t >> 6;                 // 0..7
    const int l = t & 63;
    const int mt = blockIdx.x;            // 0..255
    const int m  = mt * 32 + (l & 31);

    float s = 0.0f;
    #pragma unroll
    for (int c = 0; c < 2; ++c) {
        const int kt2 = c * 8 + w;
        const float* src = x + (size_t)m * IN_DIM + kt2 * 64 + (l >> 5) * 32;
        i32x4 lo, hi;
        #pragma unroll
        for (int j = 0; j < 4; ++j) {
            float4 v = ((const float4*)src)[j];
            s += v.x*v.x + v.y*v.y + v.z*v.z + v.w*v.w;
            lo[j] = pack4_fp8(v.x, v.y, v.z, v.w);
        }
        #pragma unroll
        for (int j = 0; j < 4; ++j) {
            float4 v = ((const float4*)src)[4 + j];
            s += v.x*v.x + v.y*v.y + v.z*v.z + v.w*v.w;
            hi[j] = pack4_fp8(v.x, v.y, v.z, v.w);
        }
        unsigned char* pan = At + ((size_t)mt * KT2 + kt2) * 2048;
        *(i32x4*)(pan + l * 16)        = lo;
        *(i32x4*)(pan + 1024 + l * 16) = hi;
    }
    // lanes l and l+32 hold the same row (different k-halves)
    s += __shfl_down(s, 32, 64);
    __shared__ float red[8][32];
    if (l < 32) red[w][l] = s;
    __syncthreads();
    if (t < 32) {
        float r = 0.0f;
        #pragma unroll
        for (int j = 0; j < 8; ++j) r += red[j][t];
        xsq[mt * 32 + t] = r;
    }

    if (blockIdx.x < 8) wsq[blockIdx.x * 512 + t] = 0.0f;   // stream order precedes tile_w atomics
}

// ---------------------------------------------------------------------------
// Kernel 2: W (fp32, IN x OUT row-major) -> fp8 B panels (transpose via LDS)
// + wsq partials (exact fp32, atomicAdd). grid (OUT/32, 4).
// ---------------------------------------------------------------------------
__global__ __launch_bounds__(256) void tile_w_kernel(
    const float* __restrict__ wgt, unsigned char* __restrict__ Bt,
    float* __restrict__ wsq)
{
    __shared__ float tile[256 * 33];      // [k][n], pad 33
    const int t  = threadIdx.x;
    const int w  = t >> 6;
    const int l  = t & 63;
    const int nt = blockIdx.x;            // 0..127
    const int q  = blockIdx.y;            // 0..3 (k quarter)
    const int n0 = nt * 32;

    {
        const int rbase = t >> 2, cg = (t & 3) * 8;
        #pragma unroll
        for (int rep = 0; rep < 4; ++rep) {
            const int r = rbase + rep * 64;
            const float* src = wgt + (size_t)(q * 256 + r) * OUT_DIM + n0 + cg;
            float4 v0 = ((const float4*)src)[0];
            float4 v1 = ((const float4*)src)[1];
            float* d = &tile[r * 33 + cg];
            d[0] = v0.x; d[1] = v0.y; d[2] = v0.z; d[3] = v0.w;
            d[4] = v1.x; d[5] = v1.y; d[6] = v1.z; d[7] = v1.w;
        }
    }
    __syncthreads();

    const int kt2 = q * 4 + w;
    const int n   = l & 31;
    const int kb  = w * 64 + (l >> 5) * 32;
    float s = 0.0f;
    i32x4 lo, hi;
    #pragma unroll
    for (int j4 = 0; j4 < 4; ++j4) {
        float f0 = tile[(kb + j4 * 4 + 0) * 33 + n];
        float f1 = tile[(kb + j4 * 4 + 1) * 33 + n];
        float f2 = tile[(kb + j4 * 4 + 2) * 33 + n];
        float f3 = tile[(kb + j4 * 4 + 3) * 33 + n];
        s += f0*f0 + f1*f1 + f2*f2 + f3*f3;
        lo[j4] = pack4_fp8(f0, f1, f2, f3);
    }
    #pragma unroll
    for (int j4 = 0; j4 < 4; ++j4) {
        float f0 = tile[(kb + 16 + j4 * 4 + 0) * 33 + n];
        float f1 = tile[(kb + 16 + j4 * 4 + 1) * 33 + n];
        float f2 = tile[(kb + 16 + j4 * 4 + 2) * 33 + n];
        float f3 = tile[(kb + 16 + j4 * 4 + 3) * 33 + n];
        s += f0*f0 + f1*f1 + f2*f2 + f3*f3;
        hi[j4] = pack4_fp8(f0, f1, f2, f3);
    }
    unsigned char* pan = Bt + ((size_t)nt * KT2 + kt2) * 2048;
    *(i32x4*)(pan + l * 16)        = lo;
    *(i32x4*)(pan + 1024 + l * 16) = hi;

    s += __shfl_down(s, 32, 64);
    __shared__ float red[4][32];
    if (l < 32) red[w][l] = s;
    __syncthreads();
    if (t < 32) atomicAdd(&wsq[n0 + t], red[0][t] + red[1][t] + red[2][t] + red[3][t]);
}

// ---------------------------------------------------------------------------
// Kernel 3: MX-fp8 GEMM. 256x256 tile, 8 waves (2 row x 4 col), each wave a
// 128x64 output = 4x2 frags of mfma_scale_f32_32x32x64 (reuse 2.67 -> LDS-read
// off the critical path). BK=64, 16 K-steps, TRIPLE-buffered LDS (96 KB) with
// counted s_waitcnt vmcnt(4) + raw s_barrier (loads stay in flight across
// barriers — T3/T4), s_setprio around the MFMA cluster (T5), XCD swizzle (T1).
// Epilogue fuses out = xsq[m] + wsq[n] - 2*cross.
// ---------------------------------------------------------------------------
__global__ __launch_bounds__(512, 2) void rbf_gemm_kernel(
    const unsigned char* __restrict__ At,   // [256*KT2][2048]
    const unsigned char* __restrict__ Bt,   // [128*KT2][2048]
    const float* __restrict__ xsq,
    const float* __restrict__ wsq,
    float* __restrict__ out)
{
    __shared__ __align__(16) unsigned char sm[3][32768];   // 96 KB: 8 A + 8 B panels x3

    const int t    = threadIdx.x;
    const int w    = t >> 6;              // 0..7
    const int l    = t & 63;
    const int l32  = l & 31;
    const int half = l >> 5;
    const int waveRow = w >> 2;           // 0..1
    const int waveCol = w & 3;            // 0..3

    // XCD-bijective swizzle: 512 wgs, 512 % 8 == 0. XCD x gets a contiguous
    // 4-row-of-bm x all-bn chunk (A slice 1 MB + B 4 MB ~ L2-resident).
    const int wg  = blockIdx.y * 32 + blockIdx.x;
    const int swz = (wg & 7) * 64 + (wg >> 3);
    const int bm  = swz >> 4;             // 0..31
    const int bn  = swz & 15;             // 0..15

    f32x16 acc[4][2];
    #pragma unroll
    for (int mi = 0; mi < 4; ++mi)
        #pragma unroll
        for (int ni = 0; ni < 2; ++ni)
            #pragma unroll
            for (int r = 0; r < 16; ++r)
                acc[mi][ni][r] = 0.0f;

    // wave w owns A panel w and B panel w of each K-step tile: 4 linear DMAs.
    const unsigned char* gaBase = At + (size_t)(bm * 8 + w) * (KT2 * 2048);
    const unsigned char* gbBase = Bt + (size_t)(bn * 8 + w) * (KT2 * 2048);

    auto stage = [&](unsigned char* base, int k) {
        const unsigned char* ga = gaBase + k * 2048;
        const unsigned char* gb = gbBase + k * 2048;
        unsigned char* As = base + w * 2048;
        unsigned char* Bs = base + 16384 + w * 2048;
        #pragma unroll
        for (int h = 0; h < 2; ++h) {
            async_copy16(ga + h * 1024 + l * 16, As + h * 1024);
            async_copy16(gb + h * 1024 + l * 16, Bs + h * 1024);
        }
    };

    auto ldfrag = [&](const unsigned char* base, int p) -> i32x8 {
        i32x4 lo = *(const i32x4*)(base + p * 2048 + l * 16);
        i32x4 hi = *(const i32x4*)(base + p * 2048 + 1024 + l * 16);
        i32x8 r;
        r[0] = lo[0]; r[1] = lo[1]; r[2] = lo[2]; r[3] = lo[3];
        r[4] = hi[0]; r[5] = hi[1]; r[6] = hi[2]; r[7] = hi[3];
        return r;
    };

    stage(sm[0], 0);          // 4 DMAs
    stage(sm[1], 1);          // 4 DMAs  (8 in flight)

    int cb = 0, sb = 2;       // compute buf = k%3, stage buf = (k+2)%3
    for (int k = 0; k < 16; ++k) {
        // Own stage(k) done: outstanding = stage(k)+stage(k+1) = 8 DMAs -> wait
        // down to 4 (never drain to 0 in the main loop; last iter drains all).
        if (k < 15) asm volatile("s_waitcnt vmcnt(4)" ::: "memory");
        else        asm volatile("s_waitcnt vmcnt(0)" ::: "memory");
        __builtin_amdgcn_s_barrier();              // all waves' stage(k) landed;
        __builtin_amdgcn_sched_barrier(0);         // no ds_read hoists above this

        // WAR-safe: buf (k+2)%3 was last read in iter k-1, and every wave is
        // past that compute (barrier above) before these DMAs issue.
        if (k <= 13) stage(sm[sb], k + 2);

        const unsigned char* As = sm[cb];
        const unsigned char* Bs = sm[cb] + 16384;
        i32x8 bf0 = ldfrag(Bs, waveCol * 2 + 0);
        i32x8 bf1 = ldfrag(Bs, waveCol * 2 + 1);
        i32x8 af[4];
        #pragma unroll
        for (int mi = 0; mi < 4; ++mi)
            af[mi] = ldfrag(As, waveRow * 4 + mi);

        __builtin_amdgcn_s_setprio(1);
        #pragma unroll
        for (int mi = 0; mi < 4; ++mi) {
            acc[mi][0] = __builtin_amdgcn_mfma_scale_f32_32x32x64_f8f6f4(
                af[mi], bf0, acc[mi][0],
                0, 0,                 // cbsz=fp8(e4m3), blgp=fp8(e4m3)
                0, 0x7F7F7F7F,        // A scales = 1.0 (E8M0 127)
                0, 0x7F7F7F7F);       // B scales = 1.0
            acc[mi][1] = __builtin_amdgcn_mfma_scale_f32_32x32x64_f8f6f4(
                af[mi], bf1, acc[mi][1],
                0, 0, 0, 0x7F7F7F7F, 0, 0x7F7F7F7F);
        }
        __builtin_amdgcn_s_setprio(0);

        cb = (cb == 2) ? 0 : cb + 1;
        sb = (sb == 2) ? 0 : sb + 1;
    }

    // Epilogue. 32x32 C/D layout: col(n)=lane&31, row(m)=(r&3)+8*(r>>2)+4*(l>>5).
    const int ncol = bn * 256 + waveCol * 64 + l32;
    const float wsn0 = wsq[ncol];
    const float wsn1 = wsq[ncol + 32];
    #pragma unroll
    for (int mi = 0; mi < 4; ++mi) {
        const int mbase = bm * 256 + waveRow * 128 + mi * 32 + 4 * half;
        #pragma unroll
        for (int r2 = 0; r2 < 4; ++r2) {
            #pragma unroll
            for (int r1 = 0; r1 < 4; ++r1) {
                const int m  = mbase + r1 + 8 * r2;
                const float xs = xsq[m];
                float* orow = out + (size_t)m * OUT_DIM + ncol;
                orow[0]  = xs + wsn0 - 2.0f * acc[mi][0][r2 * 4 + r1];
                orow[32] = xs + wsn1 - 2.0f * acc[mi][1][r2 * 4 + r1];
            }
        }
    }
}

// ---------------------------------------------------------------------------
extern "C" void kernel_launch(void* const* d_in, const int* in_sizes, int n_in,
                              void* d_out, int out_size, void* d_ws, size_t ws_size,
                              hipStream_t stream)
{
    const float* x   = (const float*)d_in[0];   // (8192, 1024) fp32
    const float* wgt = (const float*)d_in[1];   // (1024, 4096) fp32
    float* out = (float*)d_out;                 // (8192, 4096) fp32
    char*  ws  = (char*)d_ws;

    // workspace: At (8 MB) | Bt (4 MB) | xsq (32 KB) | wsq (16 KB)
    unsigned char* At = (unsigned char*)ws;
    unsigned char* Bt = (unsigned char*)(ws + (size_t)B_DIM * IN_DIM);
    float* xsq = (float*)(ws + (size_t)B_DIM * IN_DIM + (size_t)OUT_DIM * IN_DIM);
    float* wsq = xsq + B_DIM;

    tile_x_kernel<<<B_DIM / 32, 512, 0, stream>>>(x, At, xsq, wsq);
    tile_w_kernel<<<dim3(OUT_DIM / 32, 4), 256, 0, stream>>>(wgt, Bt, wsq);
    rbf_gemm_kernel<<<dim3(32, 16), 512, 0, stream>>>(At, Bt, xsq, wsq, out);
}